// Round 10
// baseline (98.961 us; speedup 1.0000x reference)
//
#include <hip/hip_runtime.h>
#include <stdint.h>

typedef float f32x4 __attribute__((ext_vector_type(4)));
typedef __bf16 bf16x8 __attribute__((ext_vector_type(8)));

#define BN_EPS 1e-5f

__device__ __forceinline__ unsigned short f2bf(float x) {
  union { float f; unsigned u; } v; v.f = x;
  unsigned r = v.u + 0x7fffu + ((v.u >> 16) & 1u);
  return (unsigned short)(r >> 16);
}

// ---------------- prep: fold BN into weights (bf16) + biases (fp32) ----------------
__global__ void prep_kernel(const float* __restrict__ W1, const float* __restrict__ b1,
                            const float* __restrict__ g1, const float* __restrict__ bt1,
                            const float* __restrict__ mu1, const float* __restrict__ v1,
                            const float* __restrict__ W2, const float* __restrict__ b2,
                            const float* __restrict__ g2, const float* __restrict__ bt2,
                            const float* __restrict__ mu2, const float* __restrict__ v2,
                            unsigned short* __restrict__ W1b, unsigned short* __restrict__ W2b,
                            float* __restrict__ bias1, float* __restrict__ bias2) {
  int tid = blockIdx.x * 256 + threadIdx.x;
  if (tid < 98304) {                       // W1: 256 x 384
    int o = tid / 384;
    float s = g1[o] * rsqrtf(v1[o] + BN_EPS);
    W1b[tid] = f2bf(W1[tid] * s);
    if (tid < 256) bias1[tid] = (b1[tid] - mu1[tid]) * (g1[tid] * rsqrtf(v1[tid] + BN_EPS)) + bt1[tid];
  } else if (tid < 98304 + 32768) {        // W2: 128 x 256
    int t = tid - 98304;
    int o = t / 256;
    float s = g2[o] * rsqrtf(v2[o] + BN_EPS);
    W2b[t] = f2bf(W2[t] * s);
    if (t < 128) bias2[t] = (b2[t] - mu2[t]) * (g2[t] * rsqrtf(v2[t] + BN_EPS)) + bt2[t];
  }
}

// ---------------- fused: 3NN + interpolate + concat + MLP, 512 threads ----------------
// r5 structure with HALVED tile: 32 points/block, 2048 blocks, 8 waves.
// LDS 25792 B + w_s/i_s -> ~26.6 KB; VGPR ~52 -> 4 blocks/CU (wave-capped, 32 waves/CU).
// Grid 2048 = exactly 8 blocks/CU = 2 full generations, no tail.
// smem union:
//   nn3 phase : sd f32[32][49] @0 (6272) | si u16[32][49] @6272 (3136) | kxyz f4[1024] @9408 (16384)
//   mlp phase : xA 32x512B @0 (bf16 cols 0..256; later y-tile; later f32 out-tile stride 132)
//               xB 32x256B @16384 (bf16 cols 256..384, staged during merge; kxyz dead then)
__global__ __launch_bounds__(512, 4)
void fp_fused_kernel(const float* __restrict__ unknown, const float* __restrict__ known,
                     const float* __restrict__ unknow_feats, const float* __restrict__ known_feats,
                     const unsigned short* __restrict__ W1b, const unsigned short* __restrict__ W2b,
                     const float* __restrict__ bias1, const float* __restrict__ bias2,
                     float* __restrict__ out) {
  __shared__ __align__(16) unsigned char smem[25792];
  __shared__ float w_s[96];
  __shared__ int   i_s[96];

  float* sd          = (float*)smem;                  // [32][49]
  unsigned short* si = (unsigned short*)(smem + 6272);
  float4* kxyz       = (float4*)(smem + 9408);
  unsigned char* xA  = smem;
  unsigned char* xB  = smem + 16384;

  int bid = blockIdx.x;
  int swz = ((bid & 7) << 8) | (bid >> 3);            // XCD-contiguous remap, bijective for 2048
  int b   = swz >> 7;
  int i0  = (swz & 127) << 5;
  int tid = threadIdx.x;

  // ---- phase 0: stage known xyz (float4-padded) + this thread's query point ----
  {
    float* kf = (float*)kxyz;
    for (int t = tid; t < 3072; t += 512) {
      int r = t / 3, c = t - r * 3;
      kf[r * 4 + c] = known[b * 3072 + t];
    }
  }
  int u  = tid & 31;                                  // point id 0..31
  int qc = tid >> 5;                                  // chunk 0..15
  const float* up = unknown + ((size_t)b * 4096 + i0 + u) * 3;
  float ax = up[0], ay = up[1], az = up[2];
  __syncthreads();

  // ---- phase 1: exact fp32 top-3 over 64 candidates x 1 point (strict <) ----
  {
    float a0 = 3e38f, a1 = 3e38f, a2 = 3e38f;
    int aj0 = 0, aj1 = 0, aj2 = 0;
    int jb = qc << 6;
    #pragma unroll 4
    for (int jj = 0; jj < 64; ++jj) {
      int j = jb + jj;
      float4 k = kxyz[j];
      float dx = ax - k.x, dy = ay - k.y, dz = az - k.z;
      float d = dx * dx + dy * dy + dz * dz;
      bool c0 = d < a0, c1 = d < a1, c2 = d < a2;
      aj2 = c1 ? aj1 : (c2 ? j : aj2);
      aj1 = c0 ? aj0 : (c1 ? j : aj1);
      aj0 = c0 ? j : aj0;
      float na2 = __builtin_amdgcn_fmed3f(a1, a2, d);
      float na1 = __builtin_amdgcn_fmed3f(a0, a1, d);
      a0 = fminf(a0, d); a1 = na1; a2 = na2;
    }
    int base = u * 49 + qc * 3;
    sd[base] = a0; sd[base + 1] = a1; sd[base + 2] = a2;
    si[base] = (unsigned short)aj0; si[base + 1] = (unsigned short)aj1; si[base + 2] = (unsigned short)aj2;
  }
  __syncthreads();

  // ---- phase 2: wave0 (tid<32) merges 48 partials/point; waves 1-7 stage xB ----
  if (tid < 32) {
    float m0 = 3e38f, m1 = 3e38f, m2 = 3e38f;
    int n0 = 0, n1 = 0, n2 = 0;
    int base = tid * 49;
    for (int e = 0; e < 48; ++e) {
      float d = sd[base + e]; int j = si[base + e];
      bool c0 = d < m0, c1 = d < m1, c2 = d < m2;
      n2 = c1 ? n1 : (c2 ? j : n2);
      n1 = c0 ? n0 : (c1 ? j : n1);
      n0 = c0 ? j : n0;
      float t2 = __builtin_amdgcn_fmed3f(m1, m2, d);
      float t1 = __builtin_amdgcn_fmed3f(m0, m1, d);
      m0 = fminf(m0, d); m1 = t1; m2 = t2;
    }
    float r0 = 1.0f / (m0 + 1e-10f);
    float r1 = 1.0f / (m1 + 1e-10f);
    float r2 = 1.0f / (m2 + 1e-10f);
    float rs = 1.0f / (r0 + r1 + r2);
    w_s[tid * 3 + 0] = r0 * rs; i_s[tid * 3 + 0] = n0;
    w_s[tid * 3 + 1] = r1 * rs; i_s[tid * 3 + 1] = n1;
    w_s[tid * 3 + 2] = r2 * rs; i_s[tid * 3 + 2] = n2;
  } else if (tid >= 64) {
    int t0 = tid - 64;                                 // 448 threads, 1024 ushort4 units
    const float4* uf = (const float4*)(unknow_feats + ((size_t)b * 4096 + i0) * 128);
    for (int t = t0; t < 1024; t += 448) {
      int p  = t >> 5;
      int cq = t & 31;
      float4 v = uf[p * 32 + cq];
      ushort4 h;
      h.x = f2bf(v.x); h.y = f2bf(v.y); h.z = f2bf(v.z); h.w = f2bf(v.w);
      int byte = p * 256 + cq * 8;
      byte ^= (p & 7) << 4;
      *(ushort4*)(xB + byte) = h;
    }
  }
  __syncthreads();

  // ---- phase 3: interpolate -> xA cols [0,256) (overwrites nn3 scratch) ----
  int l  = tid & 63;
  int q  = tid >> 6;                                  // wave id
  {
    const float4* kf = (const float4*)(known_feats + (size_t)b * 1024 * 256);
    #pragma unroll 2
    for (int po = 0; po < 4; ++po) {
      int p = po * 8 + q;
      int ia = i_s[p * 3 + 0], ib = i_s[p * 3 + 1], ic = i_s[p * 3 + 2];
      float wa = w_s[p * 3 + 0], wb = w_s[p * 3 + 1], wc = w_s[p * 3 + 2];
      float4 va = kf[ia * 64 + l];
      float4 vb = kf[ib * 64 + l];
      float4 vc = kf[ic * 64 + l];
      ushort4 h;
      h.x = f2bf(wa * va.x + wb * vb.x + wc * vc.x);
      h.y = f2bf(wa * va.y + wb * vb.y + wc * vc.y);
      h.z = f2bf(wa * va.z + wb * vb.z + wc * vc.z);
      h.w = f2bf(wa * va.w + wb * vb.w + wc * vc.w);
      int byte = p * 512 + l * 8;
      byte ^= (p & 7) << 4;
      *(ushort4*)(xA + byte) = h;
    }
  }
  __syncthreads();

  // ---- phase 4: GEMM1 (32x384)x(384->256): wave q owns cols [32q, 32q+32) ----
  int lr = l & 15;
  int lk = l >> 4;
  f32x4 acc[2][2];
  #pragma unroll
  for (int m = 0; m < 2; ++m)
    #pragma unroll
    for (int n = 0; n < 2; ++n) acc[m][n] = (f32x4){0.f, 0.f, 0.f, 0.f};

  __builtin_amdgcn_s_setprio(1);
  #pragma unroll
  for (int kk = 0; kk < 12; ++kk) {
    int kb = kk * 32 + lk * 8;                        // bf16 k index
    bf16x8 a[2];
    #pragma unroll
    for (int m = 0; m < 2; ++m) {
      int row = m * 16 + lr;
      if (kk < 8) {
        int byte = row * 512 + kb * 2;
        byte ^= (row & 7) << 4;
        a[m] = *(const bf16x8*)(xA + byte);
      } else {
        int byte = row * 256 + (kb - 256) * 2;
        byte ^= (row & 7) << 4;
        a[m] = *(const bf16x8*)(xB + byte);
      }
    }
    #pragma unroll
    for (int n = 0; n < 2; ++n) {
      int wr = q * 32 + n * 16 + lr;
      bf16x8 bb = *(const bf16x8*)(W1b + wr * 384 + kb);
      #pragma unroll
      for (int m = 0; m < 2; ++m)
        acc[m][n] = __builtin_amdgcn_mfma_f32_16x16x32_bf16(a[m], bb, acc[m][n], 0, 0, 0);
    }
  }
  __builtin_amdgcn_s_setprio(0);

  float bs1[2];
  #pragma unroll
  for (int n = 0; n < 2; ++n) bs1[n] = bias1[q * 32 + n * 16 + lr];

  __syncthreads();   // all xA/xB reads done; overwrite xA with y tile (32x256 bf16)
  #pragma unroll
  for (int m = 0; m < 2; ++m)
    #pragma unroll
    for (int n = 0; n < 2; ++n)
      #pragma unroll
      for (int i = 0; i < 4; ++i) {
        int r = m * 16 + lk * 4 + i;
        int c = q * 32 + n * 16 + lr;
        float val = fmaxf(acc[m][n][i] + bs1[n], 0.0f);
        int byte = r * 512 + c * 2;
        byte ^= (r & 7) << 4;
        *(unsigned short*)(xA + byte) = f2bf(val);
      }
  __syncthreads();

  // ---- phase 5: GEMM2 (32x256)x(256->128): wave q owns cols [16q, 16q+16) ----
  f32x4 acc2[2];
  #pragma unroll
  for (int m = 0; m < 2; ++m) acc2[m] = (f32x4){0.f, 0.f, 0.f, 0.f};

  __builtin_amdgcn_s_setprio(1);
  #pragma unroll
  for (int kk = 0; kk < 8; ++kk) {
    int kb = kk * 32 + lk * 8;
    bf16x8 a[2];
    #pragma unroll
    for (int m = 0; m < 2; ++m) {
      int row = m * 16 + lr;
      int byte = row * 512 + kb * 2;
      byte ^= (row & 7) << 4;
      a[m] = *(const bf16x8*)(xA + byte);
    }
    int wr = q * 16 + lr;
    bf16x8 bb = *(const bf16x8*)(W2b + wr * 256 + kb);
    #pragma unroll
    for (int m = 0; m < 2; ++m)
      acc2[m] = __builtin_amdgcn_mfma_f32_16x16x32_bf16(a[m], bb, acc2[m], 0, 0, 0);
  }
  __builtin_amdgcn_s_setprio(0);

  float bs2 = bias2[q * 16 + lr];

  // ---- epilogue: stage f32 out tile (stride 132), then coalesced float4 stores ----
  __syncthreads();   // all y-tile reads done
  float* ot = (float*)smem;
  #pragma unroll
  for (int m = 0; m < 2; ++m)
    #pragma unroll
    for (int i = 0; i < 4; ++i) {
      int r = m * 16 + lk * 4 + i;
      int c = q * 16 + lr;
      ot[r * 132 + c] = fmaxf(acc2[m][i] + bs2, 0.0f);
    }
  __syncthreads();
  {
    float4* out4 = (float4*)(out + ((size_t)b * 4096 + i0) * 128);
    #pragma unroll
    for (int t = tid; t < 1024; t += 512) {
      int pr = t >> 5;
      int c4 = t & 31;
      float4 v = *(const float4*)(ot + pr * 132 + c4 * 4);
      out4[pr * 32 + c4] = v;
    }
  }
}

extern "C" void kernel_launch(void* const* d_in, const int* in_sizes, int n_in,
                              void* d_out, int out_size, void* d_ws, size_t ws_size,
                              hipStream_t stream) {
  const float* unknown      = (const float*)d_in[0];
  const float* known        = (const float*)d_in[1];
  const float* unknow_feats = (const float*)d_in[2];
  const float* known_feats  = (const float*)d_in[3];
  const float* W1  = (const float*)d_in[4];
  const float* b1  = (const float*)d_in[5];
  const float* g1  = (const float*)d_in[6];
  const float* bt1 = (const float*)d_in[7];
  const float* mu1 = (const float*)d_in[8];
  const float* v1  = (const float*)d_in[9];
  const float* W2  = (const float*)d_in[10];
  const float* b2  = (const float*)d_in[11];
  const float* g2  = (const float*)d_in[12];
  const float* bt2 = (const float*)d_in[13];
  const float* mu2 = (const float*)d_in[14];
  const float* v2  = (const float*)d_in[15];

  unsigned short* W1b = (unsigned short*)d_ws;       // 98304 bf16
  unsigned short* W2b = W1b + 98304;                 // 32768 bf16
  float* bias1 = (float*)(W2b + 32768);              // 256 f32
  float* bias2 = bias1 + 256;                        // 128 f32

  prep_kernel<<<512, 256, 0, stream>>>(W1, b1, g1, bt1, mu1, v1,
                                       W2, b2, g2, bt2, mu2, v2,
                                       W1b, W2b, bias1, bias2);
  fp_fused_kernel<<<2048, 512, 0, stream>>>(unknown, known, unknow_feats, known_feats,
                                            W1b, W2b, bias1, bias2, (float*)d_out);
}

// Round 12
// 78.178 us; speedup vs baseline: 1.2658x; 1.2658x over previous
//
#include <hip/hip_runtime.h>
#include <stdint.h>

typedef float f32x4 __attribute__((ext_vector_type(4)));
typedef __bf16 bf16x8 __attribute__((ext_vector_type(8)));

#define BN_EPS 1e-5f

__device__ __forceinline__ unsigned short f2bf(float x) {
  union { float f; unsigned u; } v; v.f = x;
  unsigned r = v.u + 0x7fffu + ((v.u >> 16) & 1u);
  return (unsigned short)(r >> 16);
}

// ---------------- prep: fold BN into weights (bf16) + biases (fp32) ----------------
__global__ void prep_kernel(const float* __restrict__ W1, const float* __restrict__ b1,
                            const float* __restrict__ g1, const float* __restrict__ bt1,
                            const float* __restrict__ mu1, const float* __restrict__ v1,
                            const float* __restrict__ W2, const float* __restrict__ b2,
                            const float* __restrict__ g2, const float* __restrict__ bt2,
                            const float* __restrict__ mu2, const float* __restrict__ v2,
                            unsigned short* __restrict__ W1b, unsigned short* __restrict__ W2b,
                            float* __restrict__ bias1, float* __restrict__ bias2) {
  int tid = blockIdx.x * 256 + threadIdx.x;
  if (tid < 98304) {                       // W1: 256 x 384
    int o = tid / 384;
    float s = g1[o] * rsqrtf(v1[o] + BN_EPS);
    W1b[tid] = f2bf(W1[tid] * s);
    if (tid < 256) bias1[tid] = (b1[tid] - mu1[tid]) * (g1[tid] * rsqrtf(v1[tid] + BN_EPS)) + bt1[tid];
  } else if (tid < 98304 + 32768) {        // W2: 128 x 256
    int t = tid - 98304;
    int o = t / 256;
    float s = g2[o] * rsqrtf(v2[o] + BN_EPS);
    W2b[t] = f2bf(W2[t] * s);
    if (t < 128) bias2[t] = (b2[t] - mu2[t]) * (g2[t] * rsqrtf(v2[t] + BN_EPS)) + bt2[t];
  }
}

// ---------------- fused: 3NN + interpolate + concat + MLP, 512 threads ----------------
// r5 structure; delta: xB time-multiplexed into xA's low half. GEMM1 split:
//   GEMM1a kk0-3 (xA low bytes row*512+[0,256)) | barrier
//   GEMM1b: stage uf->bf16 into dead low slots  +  kk4-7 (xA high [256,512)) | barrier
//   GEMM1c kk8-11 (low slots). kk order 0..11 ascending = r5 accumulation order.
// Peak LDS = scan union 35200 (+ w_s/i_s) -> 4 blocks/CU; grid 1024 = one generation.
// smem union (35200 B):
//   scan  : sd f32[64][49] @0 (12544) | si u16[64][49] @12544 (6272) | kxyz f4[1024] @18816 (16384)
//   mlp   : xA 64x512B @0 (bf16; low half doubles as xB slots; later y-tile; later ot f32 s132)
__global__ __launch_bounds__(512, 4)
void fp_fused_kernel(const float* __restrict__ unknown, const float* __restrict__ known,
                     const float* __restrict__ unknow_feats, const float* __restrict__ known_feats,
                     const unsigned short* __restrict__ W1b, const unsigned short* __restrict__ W2b,
                     const float* __restrict__ bias1, const float* __restrict__ bias2,
                     float* __restrict__ out) {
  __shared__ __align__(16) unsigned char smem[35200];
  __shared__ float w_s[192];
  __shared__ int   i_s[192];

  float* sd          = (float*)smem;                  // [64][49]
  unsigned short* si = (unsigned short*)(smem + 12544);
  float4* kxyz       = (float4*)(smem + 18816);
  unsigned char* xA  = smem;

  int bid = blockIdx.x;
  int swz = ((bid & 7) << 7) | (bid >> 3);            // XCD-contiguous remap, bijective for 1024
  int b   = swz >> 6;
  int i0  = (swz & 63) << 6;
  int tid = threadIdx.x;

  // ---- phase 0: stage known xyz (float4-padded) + this thread's two query points ----
  {
    float* kf = (float*)kxyz;
    for (int t = tid; t < 3072; t += 512) {
      int r = t / 3, c = t - r * 3;
      kf[r * 4 + c] = known[b * 3072 + t];
    }
  }
  int u  = tid & 31;                                  // point pair id
  int qc = tid >> 5;                                  // chunk 0..15
  const float* up = unknown + ((size_t)b * 4096 + i0 + 2 * u) * 3;
  float ax = up[0], ay = up[1], az = up[2];
  float bx = up[3], by = up[4], bz = up[5];
  __syncthreads();

  // ---- phase 1: exact fp32 top-3 over 64 candidates x 2 points (strict <) ----
  {
    float a0 = 3e38f, a1 = 3e38f, a2 = 3e38f;
    float e0 = 3e38f, e1 = 3e38f, e2 = 3e38f;
    int aj0 = 0, aj1 = 0, aj2 = 0, ej0 = 0, ej1 = 0, ej2 = 0;
    int jb = qc << 6;
    #pragma unroll 4
    for (int jj = 0; jj < 64; ++jj) {
      int j = jb + jj;
      float4 k = kxyz[j];
      {
        float dx = ax - k.x, dy = ay - k.y, dz = az - k.z;
        float d = dx * dx + dy * dy + dz * dz;
        bool c0 = d < a0, c1 = d < a1, c2 = d < a2;
        aj2 = c1 ? aj1 : (c2 ? j : aj2);
        aj1 = c0 ? aj0 : (c1 ? j : aj1);
        aj0 = c0 ? j : aj0;
        float na2 = __builtin_amdgcn_fmed3f(a1, a2, d);
        float na1 = __builtin_amdgcn_fmed3f(a0, a1, d);
        a0 = fminf(a0, d); a1 = na1; a2 = na2;
      }
      {
        float dx = bx - k.x, dy = by - k.y, dz = bz - k.z;
        float d = dx * dx + dy * dy + dz * dz;
        bool c0 = d < e0, c1 = d < e1, c2 = d < e2;
        ej2 = c1 ? ej1 : (c2 ? j : ej2);
        ej1 = c0 ? ej0 : (c1 ? j : ej1);
        ej0 = c0 ? j : ej0;
        float na2 = __builtin_amdgcn_fmed3f(e1, e2, d);
        float na1 = __builtin_amdgcn_fmed3f(e0, e1, d);
        e0 = fminf(e0, d); e1 = na1; e2 = na2;
      }
    }
    int base = (2 * u) * 49 + qc * 3;
    sd[base] = a0; sd[base + 1] = a1; sd[base + 2] = a2;
    si[base] = (unsigned short)aj0; si[base + 1] = (unsigned short)aj1; si[base + 2] = (unsigned short)aj2;
    base += 49;
    sd[base] = e0; sd[base + 1] = e1; sd[base + 2] = e2;
    si[base] = (unsigned short)ej0; si[base + 1] = (unsigned short)ej1; si[base + 2] = (unsigned short)ej2;
  }
  __syncthreads();

  // ---- phase 2: wave0 merges 48 partials/point (chunk-ascending keeps low-index ties) ----
  if (tid < 64) {
    float m0 = 3e38f, m1 = 3e38f, m2 = 3e38f;
    int n0 = 0, n1 = 0, n2 = 0;
    int base = tid * 49;
    for (int e = 0; e < 48; ++e) {
      float d = sd[base + e]; int j = si[base + e];
      bool c0 = d < m0, c1 = d < m1, c2 = d < m2;
      n2 = c1 ? n1 : (c2 ? j : n2);
      n1 = c0 ? n0 : (c1 ? j : n1);
      n0 = c0 ? j : n0;
      float t2 = __builtin_amdgcn_fmed3f(m1, m2, d);
      float t1 = __builtin_amdgcn_fmed3f(m0, m1, d);
      m0 = fminf(m0, d); m1 = t1; m2 = t2;
    }
    float r0 = 1.0f / (m0 + 1e-10f);
    float r1 = 1.0f / (m1 + 1e-10f);
    float r2 = 1.0f / (m2 + 1e-10f);
    float rs = 1.0f / (r0 + r1 + r2);
    w_s[tid * 3 + 0] = r0 * rs; i_s[tid * 3 + 0] = n0;
    w_s[tid * 3 + 1] = r1 * rs; i_s[tid * 3 + 1] = n1;
    w_s[tid * 3 + 2] = r2 * rs; i_s[tid * 3 + 2] = n2;
  }
  __syncthreads();

  // ---- phase 3: interpolate -> xA cols [0,256) (overwrites nn3 scratch) ----
  int l = tid & 63;
  int q = tid >> 6;                                   // wave id
  {
    const float4* kf = (const float4*)(known_feats + (size_t)b * 1024 * 256);
    #pragma unroll 2
    for (int po = 0; po < 8; ++po) {
      int p = po * 8 + q;
      int ia = i_s[p * 3 + 0], ib = i_s[p * 3 + 1], ic = i_s[p * 3 + 2];
      float wa = w_s[p * 3 + 0], wb = w_s[p * 3 + 1], wc = w_s[p * 3 + 2];
      float4 va = kf[ia * 64 + l];
      float4 vb = kf[ib * 64 + l];
      float4 vc = kf[ic * 64 + l];
      ushort4 h;
      h.x = f2bf(wa * va.x + wb * vb.x + wc * vc.x);
      h.y = f2bf(wa * va.y + wb * vb.y + wc * vc.y);
      h.z = f2bf(wa * va.z + wb * vb.z + wc * vc.z);
      h.w = f2bf(wa * va.w + wb * vb.w + wc * vc.w);
      int byte = p * 512 + l * 8;
      byte ^= (p & 7) << 4;
      *(ushort4*)(xA + byte) = h;
    }
  }
  __syncthreads();

  int lr = l & 15;
  int lk = l >> 4;
  f32x4 acc[4][2];
  #pragma unroll
  for (int m = 0; m < 4; ++m)
    #pragma unroll
    for (int n = 0; n < 2; ++n) acc[m][n] = (f32x4){0.f, 0.f, 0.f, 0.f};

  // ---- phase 4a: GEMM1 kk 0..3 (xA low half: bytes row*512+[0,256)) ----
  __builtin_amdgcn_s_setprio(1);
  #pragma unroll
  for (int kk = 0; kk < 4; ++kk) {
    int kb = kk * 32 + lk * 8;
    bf16x8 a[4];
    #pragma unroll
    for (int m = 0; m < 4; ++m) {
      int row = m * 16 + lr;
      int byte = row * 512 + kb * 2;
      byte ^= (row & 7) << 4;
      a[m] = *(const bf16x8*)(xA + byte);
    }
    #pragma unroll
    for (int n = 0; n < 2; ++n) {
      int wr = q * 32 + n * 16 + lr;
      bf16x8 bb = *(const bf16x8*)(W1b + wr * 384 + kb);
      #pragma unroll
      for (int m = 0; m < 4; ++m)
        acc[m][n] = __builtin_amdgcn_mfma_f32_16x16x32_bf16(a[m], bb, acc[m][n], 0, 0, 0);
    }
  }
  __builtin_amdgcn_s_setprio(0);
  __syncthreads();   // xA low half dead (kk0-3 consumed)

  // ---- phase 4b: stage uf -> bf16 into low slots  +  GEMM1 kk 4..7 (xA high half) ----
  {
    const float4* uf = (const float4*)(unknow_feats + ((size_t)b * 4096 + i0) * 128);
    #pragma unroll
    for (int po = 0; po < 4; ++po) {
      int t = po * 512 + tid;
      int p  = t >> 5;
      int cq = t & 31;
      float4 v = uf[p * 32 + cq];
      ushort4 h;
      h.x = f2bf(v.x); h.y = f2bf(v.y); h.z = f2bf(v.z); h.w = f2bf(v.w);
      int byte = p * 512 + cq * 8;
      byte ^= (p & 7) << 4;
      *(ushort4*)(xA + byte) = h;
    }
  }
  __builtin_amdgcn_s_setprio(1);
  #pragma unroll
  for (int kk = 4; kk < 8; ++kk) {
    int kb = kk * 32 + lk * 8;
    bf16x8 a[4];
    #pragma unroll
    for (int m = 0; m < 4; ++m) {
      int row = m * 16 + lr;
      int byte = row * 512 + kb * 2;
      byte ^= (row & 7) << 4;
      a[m] = *(const bf16x8*)(xA + byte);
    }
    #pragma unroll
    for (int n = 0; n < 2; ++n) {
      int wr = q * 32 + n * 16 + lr;
      bf16x8 bb = *(const bf16x8*)(W1b + wr * 384 + kb);
      #pragma unroll
      for (int m = 0; m < 4; ++m)
        acc[m][n] = __builtin_amdgcn_mfma_f32_16x16x32_bf16(a[m], bb, acc[m][n], 0, 0, 0);
    }
  }
  __builtin_amdgcn_s_setprio(0);
  __syncthreads();   // staging visible; high half dead

  // ---- phase 4c: GEMM1 kk 8..11 (uf bf16 in low slots) ----
  __builtin_amdgcn_s_setprio(1);
  #pragma unroll
  for (int kk = 8; kk < 12; ++kk) {
    int kb = kk * 32 + lk * 8;                        // 256..376
    bf16x8 a[4];
    #pragma unroll
    for (int m = 0; m < 4; ++m) {
      int row = m * 16 + lr;
      int byte = row * 512 + (kb - 256) * 2;
      byte ^= (row & 7) << 4;
      a[m] = *(const bf16x8*)(xA + byte);
    }
    #pragma unroll
    for (int n = 0; n < 2; ++n) {
      int wr = q * 32 + n * 16 + lr;
      bf16x8 bb = *(const bf16x8*)(W1b + wr * 384 + kb);
      #pragma unroll
      for (int m = 0; m < 4; ++m)
        acc[m][n] = __builtin_amdgcn_mfma_f32_16x16x32_bf16(a[m], bb, acc[m][n], 0, 0, 0);
    }
  }
  __builtin_amdgcn_s_setprio(0);

  float bs1[2];
  #pragma unroll
  for (int n = 0; n < 2; ++n) bs1[n] = bias1[q * 32 + n * 16 + lr];

  __syncthreads();   // all xA reads done; overwrite xA with y tile (64x256 bf16)
  #pragma unroll
  for (int m = 0; m < 4; ++m)
    #pragma unroll
    for (int n = 0; n < 2; ++n)
      #pragma unroll
      for (int i = 0; i < 4; ++i) {
        int r = m * 16 + lk * 4 + i;
        int c = q * 32 + n * 16 + lr;
        float val = fmaxf(acc[m][n][i] + bs1[n], 0.0f);
        int byte = r * 512 + c * 2;
        byte ^= (r & 7) << 4;
        *(unsigned short*)(xA + byte) = f2bf(val);
      }
  __syncthreads();

  // ---- phase 5: GEMM2 (64x256)x(256->128): wave q owns cols [16q, 16q+16) ----
  f32x4 acc2[4];
  #pragma unroll
  for (int m = 0; m < 4; ++m) acc2[m] = (f32x4){0.f, 0.f, 0.f, 0.f};

  __builtin_amdgcn_s_setprio(1);
  #pragma unroll
  for (int kk = 0; kk < 8; ++kk) {
    int kb = kk * 32 + lk * 8;
    bf16x8 a[4];
    #pragma unroll
    for (int m = 0; m < 4; ++m) {
      int row = m * 16 + lr;
      int byte = row * 512 + kb * 2;
      byte ^= (row & 7) << 4;
      a[m] = *(const bf16x8*)(xA + byte);
    }
    int wr = q * 16 + lr;
    bf16x8 bb = *(const bf16x8*)(W2b + wr * 256 + kb);
    #pragma unroll
    for (int m = 0; m < 4; ++m)
      acc2[m] = __builtin_amdgcn_mfma_f32_16x16x32_bf16(a[m], bb, acc2[m], 0, 0, 0);
  }
  __builtin_amdgcn_s_setprio(0);

  float bs2 = bias2[q * 16 + lr];

  // ---- epilogue: stage f32 out tile (stride 132), then coalesced float4 stores ----
  __syncthreads();   // all y-tile reads done
  float* ot = (float*)smem;
  #pragma unroll
  for (int m = 0; m < 4; ++m)
    #pragma unroll
    for (int i = 0; i < 4; ++i) {
      int r = m * 16 + lk * 4 + i;
      int c = q * 16 + lr;
      ot[r * 132 + c] = fmaxf(acc2[m][i] + bs2, 0.0f);
    }
  __syncthreads();
  {
    float4* out4 = (float4*)(out + ((size_t)b * 4096 + i0) * 128);
    #pragma unroll
    for (int t = tid; t < 2048; t += 512) {
      int pr = t >> 5;
      int c4 = t & 31;
      float4 v = *(const float4*)(ot + pr * 132 + c4 * 4);
      out4[pr * 32 + c4] = v;
    }
  }
}

extern "C" void kernel_launch(void* const* d_in, const int* in_sizes, int n_in,
                              void* d_out, int out_size, void* d_ws, size_t ws_size,
                              hipStream_t stream) {
  const float* unknown      = (const float*)d_in[0];
  const float* known        = (const float*)d_in[1];
  const float* unknow_feats = (const float*)d_in[2];
  const float* known_feats  = (const float*)d_in[3];
  const float* W1  = (const float*)d_in[4];
  const float* b1  = (const float*)d_in[5];
  const float* g1  = (const float*)d_in[6];
  const float* bt1 = (const float*)d_in[7];
  const float* mu1 = (const float*)d_in[8];
  const float* v1  = (const float*)d_in[9];
  const float* W2  = (const float*)d_in[10];
  const float* b2  = (const float*)d_in[11];
  const float* g2  = (const float*)d_in[12];
  const float* bt2 = (const float*)d_in[13];
  const float* mu2 = (const float*)d_in[14];
  const float* v2  = (const float*)d_in[15];

  unsigned short* W1b = (unsigned short*)d_ws;       // 98304 bf16
  unsigned short* W2b = W1b + 98304;                 // 32768 bf16
  float* bias1 = (float*)(W2b + 32768);              // 256 f32
  float* bias2 = bias1 + 256;                        // 128 f32

  prep_kernel<<<512, 256, 0, stream>>>(W1, b1, g1, bt1, mu1, v1,
                                       W2, b2, g2, bt2, mu2, v2,
                                       W1b, W2b, bias1, bias2);
  fp_fused_kernel<<<1024, 512, 0, stream>>>(unknown, known, unknow_feats, known_feats,
                                            W1b, W2b, bias1, bias2, (float*)d_out);
}